// Round 4
// baseline (3169.094 us; speedup 1.0000x reference)
//
#include <hip/hip_runtime.h>

typedef short bf16x8 __attribute__((ext_vector_type(8)));
typedef float f32x4 __attribute__((ext_vector_type(4)));
typedef unsigned int u32;
typedef unsigned short u16;

#define B_ 128
#define T_ 256
#define E_ 256
#define H_ 256

#define AL(p) __hip_atomic_load((p), __ATOMIC_RELAXED, __HIP_MEMORY_SCOPE_AGENT)
#define AS(p,v) __hip_atomic_store((p), (v), __ATOMIC_RELAXED, __HIP_MEMORY_SCOPE_AGENT)

__device__ __forceinline__ u16 f2bf(float f){
  u32 x = __float_as_uint(f);
  x += 0x7FFFu + ((x >> 16) & 1u);   // RNE
  return (u16)(x >> 16);
}
__device__ __forceinline__ float bf2f(u16 v){ return __uint_as_float(((u32)v) << 16); }
__device__ __forceinline__ float sigf(float x){ return 1.0f/(1.0f + __expf(-x)); }
__device__ __forceinline__ float tanhf_(float x){ return 2.0f/(1.0f + __expf(-2.0f*x)) - 1.0f; }

// ---------------- f32 -> bf16 convert ----------------
__global__ void cvt4(const float* __restrict__ s, u16* __restrict__ d, int n4){
  int i = blockIdx.x*blockDim.x + threadIdx.x;
  int st = gridDim.x*blockDim.x;
  for (; i < n4; i += st){
    float4 f = ((const float4*)s)[i];
    ushort4 o;
    o.x=f2bf(f.x); o.y=f2bf(f.y); o.z=f2bf(f.z); o.w=f2bf(f.w);
    ((ushort4*)d)[i] = o;
  }
}

// ---------------- phase 1a: leaf buffers ----------------
__global__ __launch_bounds__(256) void leaf_kernel(
    const u16* __restrict__ xb, const u16* __restrict__ wxb, const u16* __restrict__ wgb,
    const float* __restrict__ bx, const float* __restrict__ bg,
    float* __restrict__ c_buf, u16* __restrict__ h_buf){
  int wid  = (blockIdx.x << 2) | (threadIdx.x >> 6);
  int lane = threadIdx.x & 63;
  int mt = wid >> 4, nt = wid & 15;
  int m0 = mt << 4, h0 = nt << 4;
  int lr = lane & 15, lg = lane >> 4;
  f32x4 accC = {0,0,0,0}, accG = {0,0,0,0};
  int arow = (m0 + lr) * E_;
  int wrow = (h0 + lr) * E_;
  #pragma unroll
  for (int c = 0; c < 8; ++c){
    int kb = c*32 + lg*8;
    bf16x8 af = *(const bf16x8*)(xb  + arow + kb);
    bf16x8 wx = *(const bf16x8*)(wxb + wrow + kb);
    bf16x8 wg = *(const bf16x8*)(wgb + wrow + kb);
    accC = __builtin_amdgcn_mfma_f32_16x16x32_bf16(af, wx, accC, 0,0,0);
    accG = __builtin_amdgcn_mfma_f32_16x16x32_bf16(af, wg, accG, 0,0,0);
  }
  int h = h0 + lr;
  float bxv = bx[h], bgv = bg[h];
  #pragma unroll
  for (int q = 0; q < 4; ++q){
    int m = m0 + lg*4 + q;
    float cv = accC[q] + bxv;
    float hv = sigf(accG[q] + bgv) * tanhf_(cv);
    c_buf[m*H_ + h] = cv;
    h_buf[m*H_ + h] = f2bf(hv);
  }
}

// ---------------- phase 1b: projL (leaf half of proj, incl. bias) ----------
// projL[r][pr][grow][bl] (bf16), pr = batch-pair 0..7, bl = 0..15.
// Wave owns (g, j16, bt); weights register-resident; 2 interleaved r-chains.
__global__ __launch_bounds__(256) void projl2_kernel(
    const u16* __restrict__ wrb, const float* __restrict__ br,
    const u16* __restrict__ h_buf, u16* __restrict__ projL){
  int wv = threadIdx.x >> 6, lane = threadIdx.x & 63;
  int lr = lane & 15, lg = lane >> 4;
  int id = blockIdx.x*4 + wv;           // 0..639
  int bt = id & 7, gj = id >> 3;        // gj = g*16 + j16
  int g = gj >> 4, j16 = gj & 15;
  bf16x8 af[8];
  {
    const u16* wp = wrb + (u32)(g*256 + j16*16 + lr)*512 + 256 + lg*8;
    #pragma unroll
    for (int c = 0; c < 8; ++c) af[c] = *(const bf16x8*)(wp + c*32);
  }
  float bias[4];
  #pragma unroll
  for (int q = 0; q < 4; ++q) bias[q] = br[g*256 + j16*16 + lg*4 + q];
  const u16* hb = h_buf + ((u32)(bt*16 + lr)*T_)*H_ + lg*8;

  for (int i = 0; i < 128; ++i){
    int r0 = i, r1 = i + 128;
    bool ok1 = (r1 < 255);
    int t0 = 254 - r0, t1 = 254 - r1;
    bf16x8 b0[8], b1[8];
    #pragma unroll
    for (int c = 0; c < 8; ++c) b0[c] = *(const bf16x8*)(hb + t0*H_ + c*32);
    if (ok1){
      #pragma unroll
      for (int c = 0; c < 8; ++c) b1[c] = *(const bf16x8*)(hb + t1*H_ + c*32);
    }
    f32x4 a0, a1;
    #pragma unroll
    for (int q = 0; q < 4; ++q){ a0[q] = bias[q]; a1[q] = bias[q]; }
    #pragma unroll
    for (int c = 0; c < 8; ++c){
      a0 = __builtin_amdgcn_mfma_f32_16x16x32_bf16(af[c], b0[c], a0, 0,0,0);
      if (ok1) a1 = __builtin_amdgcn_mfma_f32_16x16x32_bf16(af[c], b1[c], a1, 0,0,0);
    }
    #pragma unroll
    for (int q = 0; q < 4; ++q){
      u32 grow = (u32)(g*256 + j16*16 + lg*4 + q);
      projL[(((u32)r0*8 + bt)*1280 + grow)*16 + lr] = f2bf(a0[q]);
      if (ok1) projL[(((u32)r1*8 + bt)*1280 + grow)*16 + lr] = f2bf(a1[q]);
    }
  }
}

// ---------------- phase 2: pairwise persistent recurrence ----------------
// 16 WGs = 8 pairs x 2 halves; WG: 16 batches, all 5 gates, 128 j (own half).
// 8 waves x 64: wave v owns j-column jb + v*16 + lr across all 5 gates
// (40 weight frags in VGPRs). Elementwise fully in-register. Pairwise h
// exchange via tagged words; own-k MFMAs + projL prefetch overlap the poll.
__global__ __launch_bounds__(512, 2) void tree3_kernel(
    const u16* __restrict__ wrb, const float* __restrict__ c_buf,
    const u16* __restrict__ h_buf, const u16* __restrict__ projL,
    u32* __restrict__ h_tag, float* __restrict__ out){
  __shared__ __align__(16) char Sst[8192];   // h_state A-tile: 16 b x 256 k bf16, swizzled
  const int tid = threadIdx.x;
  const int wv = tid >> 6, lane = tid & 63;
  const int lr = lane & 15, lg = lane >> 4;
  const int pr = blockIdx.x & 7, hf = blockIdx.x >> 3;  // partners co-XCD (perf only)
  const int b0 = pr << 4;
  const int jb = hf << 7, pjb = jb ^ 128;
  const int jg = jb + wv*16 + lr;            // this lane's j (= weight row offset)
  const int cb = hf << 2;                    // own k-frag base (k = jb..jb+127)

  // resident weights: 5 gates x 8 k-frags, rows g*256+jg
  bf16x8 wf[5][8];
  #pragma unroll
  for (int g = 0; g < 5; ++g){
    const u16* wp = wrb + (u32)(g*256 + jg)*512 + lg*8;
    #pragma unroll
    for (int c = 0; c < 8; ++c) wf[g][c] = *(const bf16x8*)(wp + c*32);
  }

  // initial cell state (left operand of reduce 0 = leaf 255)
  float cst[4];
  #pragma unroll
  for (int q = 0; q < 4; ++q)
    cst[q] = c_buf[((b0 + lg*4 + q)*T_ + 255)*H_ + jg];

  // prologue: stage FULL h(leaf255) tile; prefetch projL r=0
  {
    int bl = tid >> 5, cq = tid & 31;
    bf16x8 v = *(const bf16x8*)(h_buf + ((b0+bl)*T_ + 255)*H_ + cq*8);
    *(bf16x8*)&Sst[((bl<<9) + (cq<<4)) ^ ((bl&7)<<4)] = v;
  }
  ushort4 pf[5];
  #pragma unroll
  for (int g = 0; g < 5; ++g)
    pf[g] = *(const ushort4*)(projL + (((u32)0*8 + pr)*1280 + g*256 + jg)*16 + lg*4);
  __syncthreads();

  const int blp = tid >> 5, jqp = tid & 31;  // poll identity: row blp, 4 partner cols

  for (int r = 0; r < 255; ++r){
    // c_leaf loads (used far below)
    float clf[4];
    #pragma unroll
    for (int q = 0; q < 4; ++q)
      clf[q] = c_buf[((b0 + lg*4 + q)*T_ + (254-r))*H_ + jg];

    // issue partner poll loads early
    u32 v0=0,v1=0,v2=0,v3=0;
    const u32* sp = h_tag + ((r-1)&1)*32768 + ((b0+blp)<<8) + pjb + (jqp<<2);
    if (r){ v0=AL(sp); v1=AL(sp+1); v2=AL(sp+2); v3=AL(sp+3); }

    // acc init from projL; prefetch next projL
    f32x4 acc[5];
    #pragma unroll
    for (int g = 0; g < 5; ++g){
      acc[g][0]=bf2f(pf[g].x); acc[g][1]=bf2f(pf[g].y);
      acc[g][2]=bf2f(pf[g].z); acc[g][3]=bf2f(pf[g].w);
    }
    if (r < 254){
      #pragma unroll
      for (int g = 0; g < 5; ++g)
        pf[g] = *(const ushort4*)(projL + (((u32)(r+1)*8 + pr)*1280 + g*256 + jg)*16 + lg*4);
    }

    // own-k-half MFMAs (Sst own half valid since prev bar2 / prologue)
    #pragma unroll
    for (int c = 0; c < 4; ++c){
      int off = ((lr<<9) + ((cb+c)<<6) + (lg<<4)) ^ ((lr&7)<<4);
      bf16x8 a = *(const bf16x8*)&Sst[off];
      #pragma unroll
      for (int g = 0; g < 5; ++g)
        acc[g] = __builtin_amdgcn_mfma_f32_16x16x32_bf16(a, wf[g][cb+c], acc[g], 0,0,0);
    }

    // finish poll; stage partner half into Sst
    if (r){
      const u32 want = ((u32)r) << 16;
      while ((((v0^want)|(v1^want)|(v2^want)|(v3^want)) >> 16) != 0u){
        v0=AL(sp); v1=AL(sp+1); v2=AL(sp+2); v3=AL(sp+3);
      }
      uint2 pk;
      pk.x = (v0 & 0xFFFFu) | (v1 << 16);
      pk.y = (v2 & 0xFFFFu) | (v3 << 16);
      *(uint2*)&Sst[((blp<<9) + ((pjb + (jqp<<2))<<1)) ^ ((blp&7)<<4)] = pk;
    }
    __syncthreads();   // bar1: partner half staged; own-half reads all done

    // partner-k-half MFMAs
    #pragma unroll
    for (int c = 0; c < 4; ++c){
      int cc = (cb ^ 4) + c;
      int off = ((lr<<9) + (cc<<6) + (lg<<4)) ^ ((lr&7)<<4);
      bf16x8 a = *(const bf16x8*)&Sst[off];
      #pragma unroll
      for (int g = 0; g < 5; ++g)
        acc[g] = __builtin_amdgcn_mfma_f32_16x16x32_bf16(a, wf[g][cc], acc[g], 0,0,0);
    }

    // elementwise in-register: lane owns 4 cells (b=b0+lg*4+q, j=jg)
    #pragma unroll
    for (int q = 0; q < 4; ++q){
      float iv = acc[0][q], fl = acc[1][q], fr = acc[2][q];
      float gv = acc[3][q], ov = acc[4][q];
      float cn = sigf(fl)*cst[q] + sigf(fr)*clf[q] + sigf(iv)*tanhf_(gv);
      float hn = sigf(ov)*tanhf_(cn);
      cst[q] = cn;
      if (r < 254){
        // global tagged copy for partner (issue first: partner's critical path)
        AS(h_tag + (r&1)*32768 + ((b0+lg*4+q)<<8) + jg,
           (((u32)(r+1)) << 16) | (u32)f2bf(hn));
        // own LDS copy for next step's A-tile (own-half slots dead since bar1)
        *(u16*)&Sst[(((lg*4+q)<<9) + (jg<<1)) ^ (((lg*4+q)&7)<<4)] = f2bf(hn);
      } else {
        out[(b0+lg*4+q)*H_ + jg] = hn;
      }
    }
    __syncthreads();   // bar2: partner-half reads done + own-half h_r visible
  }
}

// ---------------- launch ----------------
extern "C" void kernel_launch(void* const* d_in, const int* in_sizes, int n_in,
                              void* d_out, int out_size, void* d_ws, size_t ws_size,
                              hipStream_t stream){
  const float* x  = (const float*)d_in[0];
  const float* Wx = (const float*)d_in[2];
  const float* bx = (const float*)d_in[3];
  const float* Wg = (const float*)d_in[4];
  const float* bg = (const float*)d_in[5];
  const float* Wr = (const float*)d_in[6];
  const float* br = (const float*)d_in[7];
  float* out = (float*)d_out;

  char* ws = (char*)d_ws;
  u16*   xb    = (u16*)(ws);                  // 16,777,216 B
  u16*   wxb   = (u16*)(ws + 16777216);       //    131,072 B
  u16*   wgb   = (u16*)(ws + 16908288);       //    131,072 B
  u16*   h_buf = (u16*)(ws + 17039360);       // 16,777,216 B
  float* c_buf = (float*)(ws + 33816576);     // 33,554,432 B
  u32*   h_tag = (u32*)(ws + 67371008);       //    262,144 B
  u16*   wrb   = (u16*)(ws + 67633152);       //  1,310,720 B
  u16*   projL = (u16*)(ws + 68943872);       // 83,558,400 B -> end 152,502,272

  cvt4<<<2048, 256, 0, stream>>>(x,  xb,  8388608/4);
  cvt4<<<64,   256, 0, stream>>>(Wx, wxb, 65536/4);
  cvt4<<<64,   256, 0, stream>>>(Wg, wgb, 65536/4);
  cvt4<<<640,  256, 0, stream>>>(Wr, wrb, 655360/4);
  leaf_kernel<<<8192, 256, 0, stream>>>(xb, wxb, wgb, bx, bg, c_buf, h_buf);
  hipMemsetAsync(h_tag, 0, 262144, stream);
  projl2_kernel<<<160, 256, 0, stream>>>(wrb, br, h_buf, projL);
  tree3_kernel<<<16, 512, 0, stream>>>(wrb, c_buf, h_buf, projL, h_tag, out);
}

// Round 5
// 1264.348 us; speedup vs baseline: 2.5065x; 2.5065x over previous
//
#include <hip/hip_runtime.h>

typedef short bf16x8 __attribute__((ext_vector_type(8)));
typedef float f32x4 __attribute__((ext_vector_type(4)));
typedef unsigned int u32;
typedef unsigned short u16;

#define B_ 128
#define T_ 256
#define E_ 256
#define H_ 256

#define AL(p) __hip_atomic_load((p), __ATOMIC_RELAXED, __HIP_MEMORY_SCOPE_AGENT)
#define AS(p,v) __hip_atomic_store((p), (v), __ATOMIC_RELAXED, __HIP_MEMORY_SCOPE_AGENT)

__device__ __forceinline__ u16 f2bf(float f){
  u32 x = __float_as_uint(f);
  x += 0x7FFFu + ((x >> 16) & 1u);   // RNE
  return (u16)(x >> 16);
}
__device__ __forceinline__ float bf2f(u16 v){ return __uint_as_float(((u32)v) << 16); }
__device__ __forceinline__ float sigf(float x){ return 1.0f/(1.0f + __expf(-x)); }
__device__ __forceinline__ float tanhf_(float x){ return 2.0f/(1.0f + __expf(-2.0f*x)) - 1.0f; }

// ---------------- f32 -> bf16 convert ----------------
__global__ void cvt4(const float* __restrict__ s, u16* __restrict__ d, int n4){
  int i = blockIdx.x*blockDim.x + threadIdx.x;
  int st = gridDim.x*blockDim.x;
  for (; i < n4; i += st){
    float4 f = ((const float4*)s)[i];
    ushort4 o;
    o.x=f2bf(f.x); o.y=f2bf(f.y); o.z=f2bf(f.z); o.w=f2bf(f.w);
    ((ushort4*)d)[i] = o;
  }
}

// ---------------- phase 1a: leaf buffers ----------------
__global__ __launch_bounds__(256) void leaf_kernel(
    const u16* __restrict__ xb, const u16* __restrict__ wxb, const u16* __restrict__ wgb,
    const float* __restrict__ bx, const float* __restrict__ bg,
    float* __restrict__ c_buf, u16* __restrict__ h_buf){
  int wid  = (blockIdx.x << 2) | (threadIdx.x >> 6);
  int lane = threadIdx.x & 63;
  int mt = wid >> 4, nt = wid & 15;
  int m0 = mt << 4, h0 = nt << 4;
  int lr = lane & 15, lg = lane >> 4;
  f32x4 accC = {0,0,0,0}, accG = {0,0,0,0};
  int arow = (m0 + lr) * E_;
  int wrow = (h0 + lr) * E_;
  #pragma unroll
  for (int c = 0; c < 8; ++c){
    int kb = c*32 + lg*8;
    bf16x8 af = *(const bf16x8*)(xb  + arow + kb);
    bf16x8 wx = *(const bf16x8*)(wxb + wrow + kb);
    bf16x8 wg = *(const bf16x8*)(wgb + wrow + kb);
    accC = __builtin_amdgcn_mfma_f32_16x16x32_bf16(af, wx, accC, 0,0,0);
    accG = __builtin_amdgcn_mfma_f32_16x16x32_bf16(af, wg, accG, 0,0,0);
  }
  int h = h0 + lr;
  float bxv = bx[h], bgv = bg[h];
  #pragma unroll
  for (int q = 0; q < 4; ++q){
    int m = m0 + lg*4 + q;
    float cv = accC[q] + bxv;
    float hv = sigf(accG[q] + bgv) * tanhf_(cv);
    c_buf[m*H_ + h] = cv;
    h_buf[m*H_ + h] = f2bf(hv);
  }
}

// ---------------- phase 1b: projL (leaf half of proj, incl. bias) ----------
// projL[r][pr][grow][bl] (bf16), pr = batch-pair 0..7, bl = 0..15.
__global__ __launch_bounds__(256) void projl2_kernel(
    const u16* __restrict__ wrb, const float* __restrict__ br,
    const u16* __restrict__ h_buf, u16* __restrict__ projL){
  int wv = threadIdx.x >> 6, lane = threadIdx.x & 63;
  int lr = lane & 15, lg = lane >> 4;
  int id = blockIdx.x*4 + wv;           // 0..639
  int bt = id & 7, gj = id >> 3;        // gj = g*16 + j16
  int g = gj >> 4, j16 = gj & 15;
  bf16x8 af[8];
  {
    const u16* wp = wrb + (u32)(g*256 + j16*16 + lr)*512 + 256 + lg*8;
    #pragma unroll
    for (int c = 0; c < 8; ++c) af[c] = *(const bf16x8*)(wp + c*32);
  }
  float bias[4];
  #pragma unroll
  for (int q = 0; q < 4; ++q) bias[q] = br[g*256 + j16*16 + lg*4 + q];
  const u16* hb = h_buf + ((u32)(bt*16 + lr)*T_)*H_ + lg*8;

  for (int i = 0; i < 128; ++i){
    int r0 = i, r1 = i + 128;
    bool ok1 = (r1 < 255);
    int t0 = 254 - r0, t1 = 254 - r1;
    bf16x8 b0[8], b1[8];
    #pragma unroll
    for (int c = 0; c < 8; ++c) b0[c] = *(const bf16x8*)(hb + t0*H_ + c*32);
    if (ok1){
      #pragma unroll
      for (int c = 0; c < 8; ++c) b1[c] = *(const bf16x8*)(hb + t1*H_ + c*32);
    }
    f32x4 a0, a1;
    #pragma unroll
    for (int q = 0; q < 4; ++q){ a0[q] = bias[q]; a1[q] = bias[q]; }
    #pragma unroll
    for (int c = 0; c < 8; ++c){
      a0 = __builtin_amdgcn_mfma_f32_16x16x32_bf16(af[c], b0[c], a0, 0,0,0);
      if (ok1) a1 = __builtin_amdgcn_mfma_f32_16x16x32_bf16(af[c], b1[c], a1, 0,0,0);
    }
    #pragma unroll
    for (int q = 0; q < 4; ++q){
      u32 grow = (u32)(g*256 + j16*16 + lg*4 + q);
      projL[(((u32)r0*8 + bt)*1280 + grow)*16 + lr] = f2bf(a0[q]);
      if (ok1) projL[(((u32)r1*8 + bt)*1280 + grow)*16 + lr] = f2bf(a1[q]);
    }
  }
}

// ---------------- phase 2: pairwise persistent recurrence ----------------
// 16 WGs = 8 pairs x 2 halves; WG: 16 batches, all 5 gates, 128 j (own half).
// 8 waves: wave v owns j-column jb + v*16 + lr across all 5 gates.
// wf[g][0..3] = OWN-k-half frags (k-chunks cb..cb+3), wf[g][4..7] = PARTNER
// half (k-chunks cb^4 ..) — permuted at LOAD so all register indices are
// compile-time (R4 lesson: wf[g][cb+c] spilled the array to scratch).
__global__ __launch_bounds__(512, 2) void tree3_kernel(
    const u16* __restrict__ wrb, const float* __restrict__ c_buf,
    const u16* __restrict__ h_buf, const u16* __restrict__ projL,
    u32* __restrict__ h_tag, float* __restrict__ out){
  __shared__ __align__(16) char Sst[8192];   // h_state A-tile: 16 b x 256 k bf16, swizzled
  const int tid = threadIdx.x;
  const int wv = tid >> 6, lane = tid & 63;
  const int lr = lane & 15, lg = lane >> 4;
  const int pr = blockIdx.x & 7, hf = blockIdx.x >> 3;  // partners co-XCD (perf only)
  const int b0 = pr << 4;
  const int jb = hf << 7, pjb = jb ^ 128;
  const int jg = jb + wv*16 + lr;            // this lane's j (= weight row offset)
  const int cb = hf << 2;                    // own k-frag base (k = jb..jb+127)

  // resident weights, permuted: [0..3]=own half, [4..7]=partner half
  bf16x8 wf[5][8];
  #pragma unroll
  for (int g = 0; g < 5; ++g){
    const u16* wp = wrb + (u32)(g*256 + jg)*512 + lg*8;
    #pragma unroll
    for (int c = 0; c < 4; ++c){
      wf[g][c]   = *(const bf16x8*)(wp + (cb + c)*32);
      wf[g][4+c] = *(const bf16x8*)(wp + ((cb ^ 4) + c)*32);
    }
  }

  // initial cell state (left operand of reduce 0 = leaf 255)
  float cst[4];
  #pragma unroll
  for (int q = 0; q < 4; ++q)
    cst[q] = c_buf[((b0 + lg*4 + q)*T_ + 255)*H_ + jg];

  // prologue: stage FULL h(leaf255) tile; prefetch projL r=0
  {
    int bl = tid >> 5, cq = tid & 31;
    bf16x8 v = *(const bf16x8*)(h_buf + ((b0+bl)*T_ + 255)*H_ + cq*8);
    *(bf16x8*)&Sst[((bl<<9) + (cq<<4)) ^ ((bl&7)<<4)] = v;
  }
  ushort4 pf[5];
  #pragma unroll
  for (int g = 0; g < 5; ++g)
    pf[g] = *(const ushort4*)(projL + (((u32)0*8 + pr)*1280 + g*256 + jg)*16 + lg*4);
  __syncthreads();

  const int blp = tid >> 5, jqp = tid & 31;  // poll identity: row blp, 4 partner cols

  for (int r = 0; r < 255; ++r){
    // c_leaf loads (used far below)
    float clf[4];
    #pragma unroll
    for (int q = 0; q < 4; ++q)
      clf[q] = c_buf[((b0 + lg*4 + q)*T_ + (254-r))*H_ + jg];

    // issue partner poll loads early
    u32 v0=0,v1=0,v2=0,v3=0;
    const u32* sp = h_tag + ((r-1)&1)*32768 + ((b0+blp)<<8) + pjb + (jqp<<2);
    if (r){ v0=AL(sp); v1=AL(sp+1); v2=AL(sp+2); v3=AL(sp+3); }

    // acc init from projL; prefetch next projL
    f32x4 acc[5];
    #pragma unroll
    for (int g = 0; g < 5; ++g){
      acc[g][0]=bf2f(pf[g].x); acc[g][1]=bf2f(pf[g].y);
      acc[g][2]=bf2f(pf[g].z); acc[g][3]=bf2f(pf[g].w);
    }
    if (r < 254){
      #pragma unroll
      for (int g = 0; g < 5; ++g)
        pf[g] = *(const ushort4*)(projL + (((u32)(r+1)*8 + pr)*1280 + g*256 + jg)*16 + lg*4);
    }

    // own-k-half MFMAs (Sst own half valid since prev bar2 / prologue)
    #pragma unroll
    for (int c = 0; c < 4; ++c){
      int off = ((lr<<9) + ((cb+c)<<6) + (lg<<4)) ^ ((lr&7)<<4);
      bf16x8 a = *(const bf16x8*)&Sst[off];
      #pragma unroll
      for (int g = 0; g < 5; ++g)
        acc[g] = __builtin_amdgcn_mfma_f32_16x16x32_bf16(a, wf[g][c], acc[g], 0,0,0);
    }

    // finish poll; stage partner half into Sst
    if (r){
      const u32 want = ((u32)r) << 16;
      while ((((v0^want)|(v1^want)|(v2^want)|(v3^want)) >> 16) != 0u){
        v0=AL(sp); v1=AL(sp+1); v2=AL(sp+2); v3=AL(sp+3);
      }
      uint2 pk;
      pk.x = (v0 & 0xFFFFu) | (v1 << 16);
      pk.y = (v2 & 0xFFFFu) | (v3 << 16);
      *(uint2*)&Sst[((blp<<9) + ((pjb + (jqp<<2))<<1)) ^ ((blp&7)<<4)] = pk;
    }
    __syncthreads();   // bar1: partner half staged; own-half reads all done

    // partner-k-half MFMAs (wf[g][4..7])
    #pragma unroll
    for (int c = 0; c < 4; ++c){
      int cc = (cb ^ 4) + c;
      int off = ((lr<<9) + (cc<<6) + (lg<<4)) ^ ((lr&7)<<4);
      bf16x8 a = *(const bf16x8*)&Sst[off];
      #pragma unroll
      for (int g = 0; g < 5; ++g)
        acc[g] = __builtin_amdgcn_mfma_f32_16x16x32_bf16(a, wf[g][4+c], acc[g], 0,0,0);
    }

    // elementwise in-register: lane owns 4 cells (b=b0+lg*4+q, j=jg)
    #pragma unroll
    for (int q = 0; q < 4; ++q){
      float iv = acc[0][q], fl = acc[1][q], fr = acc[2][q];
      float gv = acc[3][q], ov = acc[4][q];
      float cn = sigf(fl)*cst[q] + sigf(fr)*clf[q] + sigf(iv)*tanhf_(gv);
      float hn = sigf(ov)*tanhf_(cn);
      cst[q] = cn;
      if (r < 254){
        AS(h_tag + (r&1)*32768 + ((b0+lg*4+q)<<8) + jg,
           (((u32)(r+1)) << 16) | (u32)f2bf(hn));
        *(u16*)&Sst[(((lg*4+q)<<9) + (jg<<1)) ^ (((lg*4+q)&7)<<4)] = f2bf(hn);
      } else {
        out[(b0+lg*4+q)*H_ + jg] = hn;
      }
    }
    __syncthreads();   // bar2: partner-half reads done + own-half h_r visible
  }
}

// ---------------- launch ----------------
extern "C" void kernel_launch(void* const* d_in, const int* in_sizes, int n_in,
                              void* d_out, int out_size, void* d_ws, size_t ws_size,
                              hipStream_t stream){
  const float* x  = (const float*)d_in[0];
  const float* Wx = (const float*)d_in[2];
  const float* bx = (const float*)d_in[3];
  const float* Wg = (const float*)d_in[4];
  const float* bg = (const float*)d_in[5];
  const float* Wr = (const float*)d_in[6];
  const float* br = (const float*)d_in[7];
  float* out = (float*)d_out;

  char* ws = (char*)d_ws;
  u16*   xb    = (u16*)(ws);                  // 16,777,216 B
  u16*   wxb   = (u16*)(ws + 16777216);       //    131,072 B
  u16*   wgb   = (u16*)(ws + 16908288);       //    131,072 B
  u16*   h_buf = (u16*)(ws + 17039360);       // 16,777,216 B
  float* c_buf = (float*)(ws + 33816576);     // 33,554,432 B
  u32*   h_tag = (u32*)(ws + 67371008);       //    262,144 B
  u16*   wrb   = (u16*)(ws + 67633152);       //  1,310,720 B
  u16*   projL = (u16*)(ws + 68943872);       // 83,558,400 B -> end 152,502,272

  cvt4<<<2048, 256, 0, stream>>>(x,  xb,  8388608/4);
  cvt4<<<64,   256, 0, stream>>>(Wx, wxb, 65536/4);
  cvt4<<<64,   256, 0, stream>>>(Wg, wgb, 65536/4);
  cvt4<<<640,  256, 0, stream>>>(Wr, wrb, 655360/4);
  leaf_kernel<<<8192, 256, 0, stream>>>(xb, wxb, wgb, bx, bg, c_buf, h_buf);
  hipMemsetAsync(h_tag, 0, 262144, stream);
  projl2_kernel<<<160, 256, 0, stream>>>(wrb, br, h_buf, projL);
  tree3_kernel<<<16, 512, 0, stream>>>(wrb, c_buf, h_buf, projL, h_tag, out);
}